// Round 1
// baseline (3824.977 us; speedup 1.0000x reference)
//
#include <hip/hip_runtime.h>
#include <hip/hip_bf16.h>
#include <math.h>

#define FH 128   // feature width of x and all hidden layers

// ---------------------------------------------------------------------------
// count in-degree (also reused to count nodes per batch group)
__global__ __launch_bounds__(256) void count_dst_kernel(const int* __restrict__ dst,
                                                        float* __restrict__ cnt, int E) {
    int e = blockIdx.x * 256 + threadIdx.x;
    if (e < E) atomicAdd(&cnt[dst[e]], 1.0f);
}

// ---------------------------------------------------------------------------
// push-scatter: aggr[dst[e]] += x[src[e]]   (32 lanes per edge, float4 each)
__global__ __launch_bounds__(256) void scatter_add_kernel(const float* __restrict__ x,
                                                          const int* __restrict__ src,
                                                          const int* __restrict__ dst,
                                                          float* __restrict__ aggr, int E) {
    int t = blockIdx.x * 256 + threadIdx.x;
    int e = t >> 5;
    if (e >= E) return;
    int f = (t & 31) << 2;
    int s = src[e], d = dst[e];
    const float4 v = *(const float4*)(x + (size_t)s * FH + f);
    float* a = aggr + (size_t)d * FH + f;
    atomicAdd(a + 0, v.x);
    atomicAdd(a + 1, v.y);
    atomicAdd(a + 2, v.z);
    atomicAdd(a + 3, v.w);
}

// ---------------------------------------------------------------------------
// fused SAGE layer: out = relu( (aggr/max(cnt,1)) @ Wl + bl + x @ Wr )
// block: 8 rows x 128 cols; in-place safe (out may alias xin): full rows are
// staged into LDS before any global write, and rows are block-exclusive.
__global__ __launch_bounds__(256) void sage_gemm_kernel(const float* __restrict__ xin,
                                                        const float* __restrict__ aggr,
                                                        const float* __restrict__ cnt,
                                                        const float* __restrict__ Wl,
                                                        const float* __restrict__ bl,
                                                        const float* __restrict__ Wr,
                                                        float* __restrict__ out, int M) {
    __shared__ float sA[8][FH];
    __shared__ float sX[8][FH];
    const int tid = threadIdx.x;
    const int r   = tid >> 5;          // 0..7 (row in tile)
    const int c4  = (tid & 31) << 2;   // 0,4,...,124 (col quad)
    const int row = blockIdx.x * 8 + r;
    if (row < M) {
        const float inv = 1.0f / fmaxf(cnt[row], 1.0f);
        const float4 a = *(const float4*)(aggr + (size_t)row * FH + c4);
        const float4 x = *(const float4*)(xin  + (size_t)row * FH + c4);
        sA[r][c4 + 0] = a.x * inv; sA[r][c4 + 1] = a.y * inv;
        sA[r][c4 + 2] = a.z * inv; sA[r][c4 + 3] = a.w * inv;
        *(float4*)&sX[r][c4] = x;
    }
    __syncthreads();
    if (row >= M) return;

    float4 acc = *(const float4*)(bl + c4);
    #pragma unroll 4
    for (int k = 0; k < FH; ++k) {
        const float av = sA[r][k];
        const float xv = sX[r][k];
        const float4 wl = *(const float4*)(Wl + k * FH + c4);
        const float4 wr = *(const float4*)(Wr + k * FH + c4);
        acc.x += av * wl.x + xv * wr.x;
        acc.y += av * wl.y + xv * wr.y;
        acc.z += av * wl.z + xv * wr.z;
        acc.w += av * wl.w + xv * wr.w;
    }
    acc.x = fmaxf(acc.x, 0.f); acc.y = fmaxf(acc.y, 0.f);
    acc.z = fmaxf(acc.z, 0.f); acc.w = fmaxf(acc.w, 0.f);
    *(float4*)(out + (size_t)row * FH + c4) = acc;
}

// ---------------------------------------------------------------------------
// global mean pool: gsum[batch[i]] += h[i]
__global__ __launch_bounds__(256) void pool_scatter_kernel(const float* __restrict__ h,
                                                           const int* __restrict__ batch,
                                                           float* __restrict__ gsum, int Nn) {
    int t = blockIdx.x * 256 + threadIdx.x;
    int node = t >> 5;
    if (node >= Nn) return;
    int f = (t & 31) << 2;
    int b = batch[node];
    const float4 v = *(const float4*)(h + (size_t)node * FH + f);
    float* g = gsum + (size_t)b * FH + f;
    atomicAdd(g + 0, v.x);
    atomicAdd(g + 1, v.y);
    atomicAdd(g + 2, v.z);
    atomicAdd(g + 3, v.w);
}

// ---------------------------------------------------------------------------
// g2 = relu( (gsum/max(gcnt,1)) @ W4 + b4 )   [G,128]x[128,64]
__global__ __launch_bounds__(256) void mlp1_kernel(const float* __restrict__ gsum,
                                                   const float* __restrict__ gcnt,
                                                   const float* __restrict__ W4,
                                                   const float* __restrict__ b4,
                                                   float* __restrict__ g2, int G) {
    int t = blockIdx.x * 256 + threadIdx.x;
    if (t >= G * 64) return;
    int g = t >> 6, j = t & 63;
    float inv = 1.0f / fmaxf(gcnt[g], 1.0f);
    float acc = b4[j];
    #pragma unroll 4
    for (int k = 0; k < FH; ++k)
        acc += gsum[g * FH + k] * inv * W4[k * 64 + j];
    g2[g * 64 + j] = fmaxf(acc, 0.f);
}

// ---------------------------------------------------------------------------
// out = log_softmax( g2 @ W5 + b5 )   [G,64]x[64,10]
__global__ __launch_bounds__(256) void mlp2_kernel(const float* __restrict__ g2,
                                                   const float* __restrict__ W5,
                                                   const float* __restrict__ b5,
                                                   float* __restrict__ out, int G) {
    int g = blockIdx.x * 256 + threadIdx.x;
    if (g >= G) return;
    float l[10];
    #pragma unroll
    for (int j = 0; j < 10; ++j) l[j] = b5[j];
    for (int k = 0; k < 64; ++k) {
        float v = g2[g * 64 + k];
        #pragma unroll
        for (int j = 0; j < 10; ++j) l[j] += v * W5[k * 10 + j];
    }
    float m = l[0];
    #pragma unroll
    for (int j = 1; j < 10; ++j) m = fmaxf(m, l[j]);
    float s = 0.f;
    #pragma unroll
    for (int j = 0; j < 10; ++j) s += expf(l[j] - m);
    float lse = m + logf(s);
    #pragma unroll
    for (int j = 0; j < 10; ++j) out[g * 10 + j] = l[j] - lse;
}

// ---------------------------------------------------------------------------
extern "C" void kernel_launch(void* const* d_in, const int* in_sizes, int n_in,
                              void* d_out, int out_size, void* d_ws, size_t ws_size,
                              hipStream_t stream) {
    const float* x     = (const float*)d_in[0];
    const int*   ei    = (const int*)d_in[1];
    const int*   batch = (const int*)d_in[2];
    const float* Wl1 = (const float*)d_in[3];
    const float* bl1 = (const float*)d_in[4];
    const float* Wr1 = (const float*)d_in[5];
    const float* Wl2 = (const float*)d_in[6];
    const float* bl2 = (const float*)d_in[7];
    const float* Wr2 = (const float*)d_in[8];
    const float* Wl3 = (const float*)d_in[9];
    const float* bl3 = (const float*)d_in[10];
    const float* Wr3 = (const float*)d_in[11];
    const float* W4  = (const float*)d_in[12];
    const float* b4  = (const float*)d_in[13];
    const float* W5  = (const float*)d_in[14];
    const float* b5  = (const float*)d_in[15];
    float* out = (float*)d_out;

    const int N = in_sizes[0] / FH;   // 50000
    const int E = in_sizes[1] / 2;    // 600000
    const int G = out_size / 10;      // 500
    const int* src = ei;
    const int* dst = ei + E;

    char* ws = (char*)d_ws;
    float* aggr = (float*)ws;                                   // N*128 f32
    float* h    = (float*)(ws + (size_t)N * FH * 4);            // N*128 f32
    float* cnt  = (float*)(ws + (size_t)2 * N * FH * 4);        // N
    float* gsum = cnt + N;                                      // G*128
    float* gcnt = gsum + (size_t)G * FH;                        // G
    float* g2   = gcnt + G;                                     // G*64

    const size_t aggrBytes = (size_t)N * FH * sizeof(float);
    const size_t tailBytes = (size_t)(N + G * FH + G) * sizeof(float);

    // zero counts + pool accumulators (every call: replays don't re-poison)
    hipMemsetAsync(cnt, 0, tailBytes, stream);

    // in-degree counts (shared by all 3 layers)
    count_dst_kernel<<<(E + 255) / 256, 256, 0, stream>>>(dst, cnt, E);

    const int scatterGrid = (E * 32 + 255) / 256;
    const int gemmGrid    = (N + 7) / 8;

    // ---- layer 1: x -> h
    hipMemsetAsync(aggr, 0, aggrBytes, stream);
    scatter_add_kernel<<<scatterGrid, 256, 0, stream>>>(x, src, dst, aggr, E);
    sage_gemm_kernel<<<gemmGrid, 256, 0, stream>>>(x, aggr, cnt, Wl1, bl1, Wr1, h, N);

    // ---- layer 2: h -> h (in-place safe)
    hipMemsetAsync(aggr, 0, aggrBytes, stream);
    scatter_add_kernel<<<scatterGrid, 256, 0, stream>>>(h, src, dst, aggr, E);
    sage_gemm_kernel<<<gemmGrid, 256, 0, stream>>>(h, aggr, cnt, Wl2, bl2, Wr2, h, N);

    // ---- layer 3: h -> h
    hipMemsetAsync(aggr, 0, aggrBytes, stream);
    scatter_add_kernel<<<scatterGrid, 256, 0, stream>>>(h, src, dst, aggr, E);
    sage_gemm_kernel<<<gemmGrid, 256, 0, stream>>>(h, aggr, cnt, Wl3, bl3, Wr3, h, N);

    // ---- global mean pool
    pool_scatter_kernel<<<(N * 32 + 255) / 256, 256, 0, stream>>>(h, batch, gsum, N);
    count_dst_kernel<<<(N + 255) / 256, 256, 0, stream>>>(batch, gcnt, N);

    // ---- MLP head + log_softmax
    mlp1_kernel<<<(G * 64 + 255) / 256, 256, 0, stream>>>(gsum, gcnt, W4, b4, g2, G);
    mlp2_kernel<<<(G + 255) / 256, 256, 0, stream>>>(g2, W5, b5, out, G);
}

// Round 2
// 1016.796 us; speedup vs baseline: 3.7618x; 3.7618x over previous
//
#include <hip/hip_runtime.h>
#include <hip/hip_bf16.h>
#include <math.h>

#define FH 128   // feature width of x and all hidden layers

// ---------------------------------------------------------------------------
// int in-degree
__global__ __launch_bounds__(256) void deg_kernel(const int* __restrict__ dst,
                                                  int* __restrict__ deg, int E) {
    int e = blockIdx.x * 256 + threadIdx.x;
    if (e < E) atomicAdd(&deg[dst[e]], 1);
}

// ---------------------------------------------------------------------------
// 3-kernel exclusive scan over deg[N] -> rowptr[N] (+ rowptr[N]=E by scan2)
__global__ __launch_bounds__(256) void scan1_kernel(const int* __restrict__ deg,
                                                    int* __restrict__ rowptr,
                                                    int* __restrict__ blockSums, int N) {
    __shared__ int lds[256];
    const int base = blockIdx.x * 1024;
    const int t = threadIdx.x;
    int v[4]; int sum = 0;
    #pragma unroll
    for (int j = 0; j < 4; ++j) {
        int idx = base + t * 4 + j;
        v[j] = (idx < N) ? deg[idx] : 0;
        sum += v[j];
    }
    lds[t] = sum; __syncthreads();
    for (int off = 1; off < 256; off <<= 1) {
        int val = lds[t];
        int add = (t >= off) ? lds[t - off] : 0;
        __syncthreads();
        lds[t] = val + add;
        __syncthreads();
    }
    int run = (t > 0) ? lds[t - 1] : 0;
    #pragma unroll
    for (int j = 0; j < 4; ++j) {
        int idx = base + t * 4 + j;
        if (idx < N) rowptr[idx] = run;
        run += v[j];
    }
    if (t == 255) blockSums[blockIdx.x] = lds[255];
}

__global__ void scan2_kernel(int* __restrict__ blockSums, int* __restrict__ rowptr,
                             int nb, int N) {
    if (threadIdx.x == 0 && blockIdx.x == 0) {
        int carry = 0;
        for (int i = 0; i < nb; ++i) {
            int s = blockSums[i];
            blockSums[i] = carry;
            carry += s;
        }
        rowptr[N] = carry;   // == E
    }
}

__global__ __launch_bounds__(256) void scan3_kernel(int* __restrict__ rowptr,
                                                    const int* __restrict__ blockSums, int N) {
    const int base = blockIdx.x * 1024;
    const int add = blockSums[blockIdx.x];
    #pragma unroll
    for (int j = 0; j < 4; ++j) {
        int idx = base + threadIdx.x * 4 + j;
        if (idx < N) rowptr[idx] += add;
    }
}

// pos = rowptr[0..N)
__global__ __launch_bounds__(256) void copy_pos_kernel(const int* __restrict__ rowptr,
                                                       int* __restrict__ pos, int N) {
    int i = blockIdx.x * 256 + threadIdx.x;
    if (i < N) pos[i] = rowptr[i];
}

// csr_src bucket fill (one int atomic per edge)
__global__ __launch_bounds__(256) void fill_csr_kernel(const int* __restrict__ src,
                                                       const int* __restrict__ dst,
                                                       int* __restrict__ pos,
                                                       int* __restrict__ csr, int E) {
    int e = blockIdx.x * 256 + threadIdx.x;
    if (e >= E) return;
    int idx = atomicAdd(&pos[dst[e]], 1);
    csr[idx] = src[e];
}

// ---------------------------------------------------------------------------
// pull aggregation with fused mean: one wave per dst node, float2 per lane
__global__ __launch_bounds__(256) void pull_mean_kernel(const float* __restrict__ x,
                                                        const int* __restrict__ rowptr,
                                                        const int* __restrict__ csr,
                                                        float* __restrict__ aggr, int N) {
    const int v = (blockIdx.x * 256 + threadIdx.x) >> 6;
    if (v >= N) return;
    const int lane = threadIdx.x & 63;
    const int beg = rowptr[v], end = rowptr[v + 1];
    const float* xp = x + lane * 2;
    float2 acc = make_float2(0.f, 0.f);
    for (int i = beg; i < end; ++i) {
        const int s = csr[i];
        const float2 w = *(const float2*)(xp + (size_t)s * FH);
        acc.x += w.x; acc.y += w.y;
    }
    const float inv = 1.0f / (float)max(end - beg, 1);
    *(float2*)(aggr + (size_t)v * FH + lane * 2) = make_float2(acc.x * inv, acc.y * inv);
}

// ---------------------------------------------------------------------------
// fused SAGE layer: out = relu( aggr @ Wl + bl + x @ Wr )   (aggr already mean)
// in-place safe (out may alias xin): rows staged in LDS, block-exclusive rows.
__global__ __launch_bounds__(256) void sage_gemm_kernel(const float* __restrict__ xin,
                                                        const float* __restrict__ aggr,
                                                        const float* __restrict__ Wl,
                                                        const float* __restrict__ bl,
                                                        const float* __restrict__ Wr,
                                                        float* __restrict__ out, int M) {
    __shared__ float sA[8][FH];
    __shared__ float sX[8][FH];
    const int tid = threadIdx.x;
    const int r   = tid >> 5;          // 0..7
    const int c4  = (tid & 31) << 2;   // 0,4,...,124
    const int row = blockIdx.x * 8 + r;
    if (row < M) {
        *(float4*)&sA[r][c4] = *(const float4*)(aggr + (size_t)row * FH + c4);
        *(float4*)&sX[r][c4] = *(const float4*)(xin  + (size_t)row * FH + c4);
    }
    __syncthreads();
    if (row >= M) return;

    float4 acc = *(const float4*)(bl + c4);
    #pragma unroll 4
    for (int k = 0; k < FH; ++k) {
        const float av = sA[r][k];
        const float xv = sX[r][k];
        const float4 wl = *(const float4*)(Wl + k * FH + c4);
        const float4 wr = *(const float4*)(Wr + k * FH + c4);
        acc.x += av * wl.x + xv * wr.x;
        acc.y += av * wl.y + xv * wr.y;
        acc.z += av * wl.z + xv * wr.z;
        acc.w += av * wl.w + xv * wr.w;
    }
    acc.x = fmaxf(acc.x, 0.f); acc.y = fmaxf(acc.y, 0.f);
    acc.z = fmaxf(acc.z, 0.f); acc.w = fmaxf(acc.w, 0.f);
    *(float4*)(out + (size_t)row * FH + c4) = acc;
}

// ---------------------------------------------------------------------------
// global mean pool: gsum[batch[i]] += h[i]  (atomics; revisit if hot)
__global__ __launch_bounds__(256) void pool_scatter_kernel(const float* __restrict__ h,
                                                           const int* __restrict__ batch,
                                                           float* __restrict__ gsum, int Nn) {
    int t = blockIdx.x * 256 + threadIdx.x;
    int node = t >> 5;
    if (node >= Nn) return;
    int f = (t & 31) << 2;
    int b = batch[node];
    const float4 v = *(const float4*)(h + (size_t)node * FH + f);
    float* g = gsum + (size_t)b * FH + f;
    atomicAdd(g + 0, v.x);
    atomicAdd(g + 1, v.y);
    atomicAdd(g + 2, v.z);
    atomicAdd(g + 3, v.w);
}

__global__ __launch_bounds__(256) void count_batch_kernel(const int* __restrict__ batch,
                                                          float* __restrict__ gcnt, int Nn) {
    int i = blockIdx.x * 256 + threadIdx.x;
    if (i < Nn) atomicAdd(&gcnt[batch[i]], 1.0f);
}

// ---------------------------------------------------------------------------
// g2 = relu( (gsum/max(gcnt,1)) @ W4 + b4 )
__global__ __launch_bounds__(256) void mlp1_kernel(const float* __restrict__ gsum,
                                                   const float* __restrict__ gcnt,
                                                   const float* __restrict__ W4,
                                                   const float* __restrict__ b4,
                                                   float* __restrict__ g2, int G) {
    int t = blockIdx.x * 256 + threadIdx.x;
    if (t >= G * 64) return;
    int g = t >> 6, j = t & 63;
    float inv = 1.0f / fmaxf(gcnt[g], 1.0f);
    float acc = b4[j];
    #pragma unroll 4
    for (int k = 0; k < FH; ++k)
        acc += gsum[g * FH + k] * inv * W4[k * 64 + j];
    g2[g * 64 + j] = fmaxf(acc, 0.f);
}

// out = log_softmax( g2 @ W5 + b5 )
__global__ __launch_bounds__(256) void mlp2_kernel(const float* __restrict__ g2,
                                                   const float* __restrict__ W5,
                                                   const float* __restrict__ b5,
                                                   float* __restrict__ out, int G) {
    int g = blockIdx.x * 256 + threadIdx.x;
    if (g >= G) return;
    float l[10];
    #pragma unroll
    for (int j = 0; j < 10; ++j) l[j] = b5[j];
    for (int k = 0; k < 64; ++k) {
        float v = g2[g * 64 + k];
        #pragma unroll
        for (int j = 0; j < 10; ++j) l[j] += v * W5[k * 10 + j];
    }
    float m = l[0];
    #pragma unroll
    for (int j = 1; j < 10; ++j) m = fmaxf(m, l[j]);
    float s = 0.f;
    #pragma unroll
    for (int j = 0; j < 10; ++j) s += expf(l[j] - m);
    float lse = m + logf(s);
    #pragma unroll
    for (int j = 0; j < 10; ++j) out[g * 10 + j] = l[j] - lse;
}

// ---------------------------------------------------------------------------
extern "C" void kernel_launch(void* const* d_in, const int* in_sizes, int n_in,
                              void* d_out, int out_size, void* d_ws, size_t ws_size,
                              hipStream_t stream) {
    const float* x     = (const float*)d_in[0];
    const int*   ei    = (const int*)d_in[1];
    const int*   batch = (const int*)d_in[2];
    const float* Wl1 = (const float*)d_in[3];
    const float* bl1 = (const float*)d_in[4];
    const float* Wr1 = (const float*)d_in[5];
    const float* Wl2 = (const float*)d_in[6];
    const float* bl2 = (const float*)d_in[7];
    const float* Wr2 = (const float*)d_in[8];
    const float* Wl3 = (const float*)d_in[9];
    const float* bl3 = (const float*)d_in[10];
    const float* Wr3 = (const float*)d_in[11];
    const float* W4  = (const float*)d_in[12];
    const float* b4  = (const float*)d_in[13];
    const float* W5  = (const float*)d_in[14];
    const float* b5  = (const float*)d_in[15];
    float* out = (float*)d_out;

    const int N = in_sizes[0] / FH;   // 50000
    const int E = in_sizes[1] / 2;    // 600000
    const int G = out_size / 10;      // 500
    const int* src = ei;
    const int* dst = ei + E;

    // ---- workspace layout
    char* ws = (char*)d_ws;
    const size_t NA = (size_t)N * FH * sizeof(float);
    float* aggr = (float*)ws;                       // N*128 f32
    float* h    = (float*)(ws + NA);                // N*128 f32
    char*  p    = ws + 2 * NA;
    int* deg      = (int*)p;            p += (size_t)N * 4;
    int* rowptr   = (int*)p;            p += (size_t)(N + 1) * 4;
    int* pos      = (int*)p;            p += (size_t)N * 4;
    int* csr      = (int*)p;            p += (size_t)E * 4;
    int* blockSums= (int*)p;            p += 256 * 4;
    float* gsum   = (float*)p;          p += (size_t)G * FH * 4;
    float* gcnt   = (float*)p;          p += (size_t)G * 4;
    float* g2     = (float*)p;

    const int nb = (N + 1023) / 1024;   // scan blocks

    // ---- zero what must be zero every call
    hipMemsetAsync(deg, 0, (size_t)N * 4, stream);
    hipMemsetAsync(gsum, 0, (size_t)(G * FH + G) * 4, stream);

    // ---- CSR build (once per call, reused by all 3 layers)
    deg_kernel<<<(E + 255) / 256, 256, 0, stream>>>(dst, deg, E);
    scan1_kernel<<<nb, 256, 0, stream>>>(deg, rowptr, blockSums, N);
    scan2_kernel<<<1, 64, 0, stream>>>(blockSums, rowptr, nb, N);
    scan3_kernel<<<nb, 256, 0, stream>>>(rowptr, blockSums, N);
    copy_pos_kernel<<<(N + 255) / 256, 256, 0, stream>>>(rowptr, pos, N);
    fill_csr_kernel<<<(E + 255) / 256, 256, 0, stream>>>(src, dst, pos, csr, E);

    const int pullGrid = (N * 64 + 255) / 256;
    const int gemmGrid = (N + 7) / 8;

    // ---- layer 1: x -> h
    pull_mean_kernel<<<pullGrid, 256, 0, stream>>>(x, rowptr, csr, aggr, N);
    sage_gemm_kernel<<<gemmGrid, 256, 0, stream>>>(x, aggr, Wl1, bl1, Wr1, h, N);

    // ---- layer 2: h -> h (in-place safe)
    pull_mean_kernel<<<pullGrid, 256, 0, stream>>>(h, rowptr, csr, aggr, N);
    sage_gemm_kernel<<<gemmGrid, 256, 0, stream>>>(h, aggr, Wl2, bl2, Wr2, h, N);

    // ---- layer 3: h -> h
    pull_mean_kernel<<<pullGrid, 256, 0, stream>>>(h, rowptr, csr, aggr, N);
    sage_gemm_kernel<<<gemmGrid, 256, 0, stream>>>(h, aggr, Wl3, bl3, Wr3, h, N);

    // ---- global mean pool
    pool_scatter_kernel<<<(N * 32 + 255) / 256, 256, 0, stream>>>(h, batch, gsum, N);
    count_batch_kernel<<<(N + 255) / 256, 256, 0, stream>>>(batch, gcnt, N);

    // ---- MLP head + log_softmax
    mlp1_kernel<<<(G * 64 + 255) / 256, 256, 0, stream>>>(gsum, gcnt, W4, b4, g2, G);
    mlp2_kernel<<<(G + 255) / 256, 256, 0, stream>>>(g2, W5, b5, out, G);
}

// Round 3
// 494.958 us; speedup vs baseline: 7.7279x; 2.0543x over previous
//
#include <hip/hip_runtime.h>
#include <hip/hip_bf16.h>
#include <math.h>

#define FH 128   // feature width of x and all hidden layers

typedef __attribute__((ext_vector_type(8))) short short8v;   // 8 bf16 (4 VGPRs)
typedef __attribute__((ext_vector_type(4))) float float4v;
typedef unsigned short ushort_t;
typedef unsigned int   uint32;

__device__ __forceinline__ ushort_t f2bf(float f) {          // RNE float->bf16
    uint32 u = __builtin_bit_cast(uint32, f);
    u += 0x7fffu + ((u >> 16) & 1u);
    return (ushort_t)(u >> 16);
}
__device__ __forceinline__ float bf_lo(uint32 w) { return __builtin_bit_cast(float, w << 16); }
__device__ __forceinline__ float bf_hi(uint32 w) { return __builtin_bit_cast(float, w & 0xffff0000u); }

// ---------------------------------------------------------------------------
// fp32 -> bf16 bulk convert (8 elems/thread)
__global__ __launch_bounds__(256) void cvt_bf16_kernel(const float* __restrict__ x,
                                                       ushort_t* __restrict__ xb, size_t n) {
    size_t base = ((size_t)blockIdx.x * 256 + threadIdx.x) * 8;
    if (base >= n) return;
    const float4 a = *(const float4*)(x + base);
    const float4 b = *(const float4*)(x + base + 4);
    ushort_t o[8] = {f2bf(a.x), f2bf(a.y), f2bf(a.z), f2bf(a.w),
                     f2bf(b.x), f2bf(b.y), f2bf(b.z), f2bf(b.w)};
    *(uint4*)(xb + base) = *(const uint4*)o;
}

// ---------------------------------------------------------------------------
// CSR build
__global__ __launch_bounds__(256) void deg_kernel(const int* __restrict__ dst,
                                                  int* __restrict__ deg, int E) {
    int e = blockIdx.x * 256 + threadIdx.x;
    if (e < E) atomicAdd(&deg[dst[e]], 1);
}

__global__ __launch_bounds__(256) void scan1_kernel(const int* __restrict__ deg,
                                                    int* __restrict__ rowptr,
                                                    int* __restrict__ blockSums, int N) {
    __shared__ int lds[256];
    const int base = blockIdx.x * 1024;
    const int t = threadIdx.x;
    int v[4]; int sum = 0;
    #pragma unroll
    for (int j = 0; j < 4; ++j) {
        int idx = base + t * 4 + j;
        v[j] = (idx < N) ? deg[idx] : 0;
        sum += v[j];
    }
    lds[t] = sum; __syncthreads();
    for (int off = 1; off < 256; off <<= 1) {
        int val = lds[t];
        int add = (t >= off) ? lds[t - off] : 0;
        __syncthreads();
        lds[t] = val + add;
        __syncthreads();
    }
    int run = (t > 0) ? lds[t - 1] : 0;
    #pragma unroll
    for (int j = 0; j < 4; ++j) {
        int idx = base + t * 4 + j;
        if (idx < N) rowptr[idx] = run;
        run += v[j];
    }
    if (t == 255) blockSums[blockIdx.x] = lds[255];
}

__global__ void scan2_kernel(int* __restrict__ blockSums, int* __restrict__ rowptr,
                             int nb, int N) {
    if (threadIdx.x == 0 && blockIdx.x == 0) {
        int carry = 0;
        for (int i = 0; i < nb; ++i) {
            int s = blockSums[i];
            blockSums[i] = carry;
            carry += s;
        }
        rowptr[N] = carry;   // == E
    }
}

__global__ __launch_bounds__(256) void scan3_kernel(int* __restrict__ rowptr,
                                                    const int* __restrict__ blockSums, int N) {
    const int base = blockIdx.x * 1024;
    const int add = blockSums[blockIdx.x];
    #pragma unroll
    for (int j = 0; j < 4; ++j) {
        int idx = base + threadIdx.x * 4 + j;
        if (idx < N) rowptr[idx] += add;
    }
}

__global__ __launch_bounds__(256) void copy_pos_kernel(const int* __restrict__ rowptr,
                                                       int* __restrict__ pos, int N) {
    int i = blockIdx.x * 256 + threadIdx.x;
    if (i < N) pos[i] = rowptr[i];
}

__global__ __launch_bounds__(256) void fill_csr_kernel(const int* __restrict__ src,
                                                       const int* __restrict__ dst,
                                                       int* __restrict__ pos,
                                                       int* __restrict__ csr, int E) {
    int e = blockIdx.x * 256 + threadIdx.x;
    if (e >= E) return;
    int idx = atomicAdd(&pos[dst[e]], 1);
    csr[idx] = src[e];
}

// ---------------------------------------------------------------------------
// pull aggregation (bf16 in/out, fp32 accumulate): one wave per dst node
__global__ __launch_bounds__(256) void pull_mean_kernel(const ushort_t* __restrict__ x,
                                                        const int* __restrict__ rowptr,
                                                        const int* __restrict__ csr,
                                                        ushort_t* __restrict__ aggr, int N) {
    const int v = (blockIdx.x * 256 + threadIdx.x) >> 6;
    if (v >= N) return;
    const int lane = threadIdx.x & 63;
    const int beg = rowptr[v], end = rowptr[v + 1];
    const uint32* xp = (const uint32*)x + lane;        // 2 bf16 per u32; row = 64 u32
    float ax = 0.f, ay = 0.f;
    for (int i = beg; i < end; ++i) {
        const uint32 w = xp[(size_t)csr[i] * 64];
        ax += bf_lo(w); ay += bf_hi(w);
    }
    const float inv = 1.0f / (float)max(end - beg, 1);
    const uint32 o = (uint32)f2bf(ax * inv) | ((uint32)f2bf(ay * inv) << 16);
    ((uint32*)aggr)[(size_t)v * 64 + lane] = o;
}

// ---------------------------------------------------------------------------
// pack W = [Wl;Wr] (256x128 fp32) into MFMA-fragment-ordered bf16:
// Bp[((nt*8+kt)*64 + lane)*8 + j] = W[k][n],
//   nt=n>>4, kt=k>>5, lane=(n&15)+16*((k>>3)&3), j=k&7
__global__ __launch_bounds__(256) void pack_w_kernel(const float* __restrict__ Wl,
                                                     const float* __restrict__ Wr,
                                                     ushort_t* __restrict__ Bp) {
    int t = blockIdx.x * 256 + threadIdx.x;
    if (t >= 256 * FH) return;
    int k = t >> 7, n = t & 127;
    float v = (k < FH) ? Wl[k * FH + n] : Wr[(k - FH) * FH + n];
    int nt = n >> 4, kt = k >> 5;
    int lane = (n & 15) + (((k >> 3) & 3) << 4);
    int j = k & 7;
    Bp[(((nt * 8 + kt) * 64) + lane) * 8 + j] = f2bf(v);
}

// ---------------------------------------------------------------------------
// fused SAGE layer via MFMA: out = relu([aggr|xin](Mx256) @ W(256x128) + bl)
// 4 waves/block, 16 rows/wave; full weight tile staged in LDS (64KB).
// In-place safe: each wave's 16 rows are register-staged before any store.
__global__ __launch_bounds__(256) void sage_mfma_kernel(const ushort_t* __restrict__ xin,
                                                        const ushort_t* __restrict__ aggr,
                                                        const ushort_t* __restrict__ Bp,
                                                        const float* __restrict__ bl,
                                                        ushort_t* __restrict__ out, int M) {
    __shared__ ushort_t sB[8 * 8 * 64 * 8];   // 64 KB
    const int tid = threadIdx.x;
    {   // cooperative 64KB load: 4096 x 16B
        const uint4* s = (const uint4*)Bp;
        uint4* d = (uint4*)sB;
        #pragma unroll
        for (int i = 0; i < 16; ++i)
            d[tid + 256 * i] = s[tid + 256 * i];
    }
    __syncthreads();

    const int wave = tid >> 6;
    const int lane = tid & 63;
    const int grp  = lane >> 4;
    const int rowBase = (blockIdx.x * 4 + wave) * 16;
    if (rowBase >= M) return;
    const int arow = min(rowBase + (lane & 15), M - 1);

    short8v afrag[8];
    #pragma unroll
    for (int kt = 0; kt < 4; ++kt)
        afrag[kt] = *(const short8v*)(aggr + (size_t)arow * FH + kt * 32 + grp * 8);
    #pragma unroll
    for (int kt = 0; kt < 4; ++kt)
        afrag[4 + kt] = *(const short8v*)(xin + (size_t)arow * FH + kt * 32 + grp * 8);

    #pragma unroll
    for (int nt = 0; nt < 8; ++nt) {
        float4v acc = {0.f, 0.f, 0.f, 0.f};
        #pragma unroll
        for (int kt = 0; kt < 8; ++kt) {
            const short8v b = *(const short8v*)(sB + (((nt * 8 + kt) * 64) + lane) * 8);
            acc = __builtin_amdgcn_mfma_f32_16x16x32_bf16(afrag[kt], b, acc, 0, 0, 0);
        }
        const int col = nt * 16 + (lane & 15);
        const float bias = bl[col];
        #pragma unroll
        for (int r = 0; r < 4; ++r) {
            const int row = rowBase + grp * 4 + r;
            if (row < M)
                out[(size_t)row * FH + col] = f2bf(fmaxf(acc[r] + bias, 0.f));
        }
    }
}

// ---------------------------------------------------------------------------
// global mean pool from bf16 h
__global__ __launch_bounds__(256) void pool_scatter_kernel(const ushort_t* __restrict__ h,
                                                           const int* __restrict__ batch,
                                                           float* __restrict__ gsum, int Nn) {
    int t = blockIdx.x * 256 + threadIdx.x;
    int node = t >> 5;
    if (node >= Nn) return;
    int f = (t & 31) << 2;
    int b = batch[node];
    const uint32* hp = (const uint32*)(h + (size_t)node * FH + f);
    const uint32 w0 = hp[0], w1 = hp[1];
    float* g = gsum + (size_t)b * FH + f;
    atomicAdd(g + 0, bf_lo(w0));
    atomicAdd(g + 1, bf_hi(w0));
    atomicAdd(g + 2, bf_lo(w1));
    atomicAdd(g + 3, bf_hi(w1));
}

__global__ __launch_bounds__(256) void count_batch_kernel(const int* __restrict__ batch,
                                                          float* __restrict__ gcnt, int Nn) {
    int i = blockIdx.x * 256 + threadIdx.x;
    if (i < Nn) atomicAdd(&gcnt[batch[i]], 1.0f);
}

// ---------------------------------------------------------------------------
__global__ __launch_bounds__(256) void mlp1_kernel(const float* __restrict__ gsum,
                                                   const float* __restrict__ gcnt,
                                                   const float* __restrict__ W4,
                                                   const float* __restrict__ b4,
                                                   float* __restrict__ g2, int G) {
    int t = blockIdx.x * 256 + threadIdx.x;
    if (t >= G * 64) return;
    int g = t >> 6, j = t & 63;
    float inv = 1.0f / fmaxf(gcnt[g], 1.0f);
    float acc = b4[j];
    #pragma unroll 4
    for (int k = 0; k < FH; ++k)
        acc += gsum[g * FH + k] * inv * W4[k * 64 + j];
    g2[g * 64 + j] = fmaxf(acc, 0.f);
}

__global__ __launch_bounds__(256) void mlp2_kernel(const float* __restrict__ g2,
                                                   const float* __restrict__ W5,
                                                   const float* __restrict__ b5,
                                                   float* __restrict__ out, int G) {
    int g = blockIdx.x * 256 + threadIdx.x;
    if (g >= G) return;
    float l[10];
    #pragma unroll
    for (int j = 0; j < 10; ++j) l[j] = b5[j];
    for (int k = 0; k < 64; ++k) {
        float v = g2[g * 64 + k];
        #pragma unroll
        for (int j = 0; j < 10; ++j) l[j] += v * W5[k * 10 + j];
    }
    float m = l[0];
    #pragma unroll
    for (int j = 1; j < 10; ++j) m = fmaxf(m, l[j]);
    float s = 0.f;
    #pragma unroll
    for (int j = 0; j < 10; ++j) s += expf(l[j] - m);
    float lse = m + logf(s);
    #pragma unroll
    for (int j = 0; j < 10; ++j) out[g * 10 + j] = l[j] - lse;
}

// ---------------------------------------------------------------------------
extern "C" void kernel_launch(void* const* d_in, const int* in_sizes, int n_in,
                              void* d_out, int out_size, void* d_ws, size_t ws_size,
                              hipStream_t stream) {
    const float* x     = (const float*)d_in[0];
    const int*   ei    = (const int*)d_in[1];
    const int*   batch = (const int*)d_in[2];
    const float* Wl1 = (const float*)d_in[3];
    const float* bl1 = (const float*)d_in[4];
    const float* Wr1 = (const float*)d_in[5];
    const float* Wl2 = (const float*)d_in[6];
    const float* bl2 = (const float*)d_in[7];
    const float* Wr2 = (const float*)d_in[8];
    const float* Wl3 = (const float*)d_in[9];
    const float* bl3 = (const float*)d_in[10];
    const float* Wr3 = (const float*)d_in[11];
    const float* W4  = (const float*)d_in[12];
    const float* b4  = (const float*)d_in[13];
    const float* W5  = (const float*)d_in[14];
    const float* b5  = (const float*)d_in[15];
    float* out = (float*)d_out;

    const int N = in_sizes[0] / FH;   // 50000
    const int E = in_sizes[1] / 2;    // 600000
    const int G = out_size / 10;      // 500
    const int* src = ei;
    const int* dst = ei + E;

    // ---- workspace layout (256B-aligned chunks)
    char* p = (char*)d_ws;
    auto take = [&](size_t bytes) { char* q = p; p += (bytes + 255) & ~(size_t)255; return q; };
    ushort_t* xb    = (ushort_t*)take((size_t)N * FH * 2);
    ushort_t* h     = (ushort_t*)take((size_t)N * FH * 2);
    ushort_t* aggrb = (ushort_t*)take((size_t)N * FH * 2);
    int* deg        = (int*)take((size_t)N * 4);
    int* rowptr     = (int*)take((size_t)(N + 1) * 4);
    int* pos        = (int*)take((size_t)N * 4);
    int* csr        = (int*)take((size_t)E * 4);
    int* blockSums  = (int*)take(256 * 4);
    ushort_t* Bp1   = (ushort_t*)take(256 * FH * 2);
    ushort_t* Bp2   = (ushort_t*)take(256 * FH * 2);
    ushort_t* Bp3   = (ushort_t*)take(256 * FH * 2);
    float* gsum     = (float*)take((size_t)G * FH * 4);
    float* gcnt     = (float*)take((size_t)G * 4);
    float* g2       = (float*)take((size_t)G * 64 * 4);

    const int nb = (N + 1023) / 1024;

    hipMemsetAsync(deg, 0, (size_t)N * 4, stream);
    hipMemsetAsync(gsum, 0, (size_t)G * FH * 4, stream);
    hipMemsetAsync(gcnt, 0, (size_t)G * 4, stream);

    // ---- one-time converts / packs
    cvt_bf16_kernel<<<(N * FH / 8 + 255) / 256, 256, 0, stream>>>(x, xb, (size_t)N * FH);
    pack_w_kernel<<<(256 * FH + 255) / 256, 256, 0, stream>>>(Wl1, Wr1, Bp1);
    pack_w_kernel<<<(256 * FH + 255) / 256, 256, 0, stream>>>(Wl2, Wr2, Bp2);
    pack_w_kernel<<<(256 * FH + 255) / 256, 256, 0, stream>>>(Wl3, Wr3, Bp3);

    // ---- CSR build
    deg_kernel<<<(E + 255) / 256, 256, 0, stream>>>(dst, deg, E);
    scan1_kernel<<<nb, 256, 0, stream>>>(deg, rowptr, blockSums, N);
    scan2_kernel<<<1, 64, 0, stream>>>(blockSums, rowptr, nb, N);
    scan3_kernel<<<nb, 256, 0, stream>>>(rowptr, blockSums, N);
    copy_pos_kernel<<<(N + 255) / 256, 256, 0, stream>>>(rowptr, pos, N);
    fill_csr_kernel<<<(E + 255) / 256, 256, 0, stream>>>(src, dst, pos, csr, E);

    const int pullGrid = (N * 64 + 255) / 256;
    const int gemmGrid = (N + 63) / 64;

    // ---- 3 SAGE layers (bf16 features, fp32 accum)
    pull_mean_kernel<<<pullGrid, 256, 0, stream>>>(xb, rowptr, csr, aggrb, N);
    sage_mfma_kernel<<<gemmGrid, 256, 0, stream>>>(xb, aggrb, Bp1, bl1, h, N);

    pull_mean_kernel<<<pullGrid, 256, 0, stream>>>(h, rowptr, csr, aggrb, N);
    sage_mfma_kernel<<<gemmGrid, 256, 0, stream>>>(h, aggrb, Bp2, bl2, h, N);

    pull_mean_kernel<<<pullGrid, 256, 0, stream>>>(h, rowptr, csr, aggrb, N);
    sage_mfma_kernel<<<gemmGrid, 256, 0, stream>>>(h, aggrb, Bp3, bl3, h, N);

    // ---- global mean pool + head
    pool_scatter_kernel<<<(N * 32 + 255) / 256, 256, 0, stream>>>(h, batch, gsum, N);
    count_batch_kernel<<<(N + 255) / 256, 256, 0, stream>>>(batch, gcnt, N);
    mlp1_kernel<<<(G * 64 + 255) / 256, 256, 0, stream>>>(gsum, gcnt, W4, b4, g2, G);
    mlp2_kernel<<<(G + 255) / 256, 256, 0, stream>>>(g2, W5, b5, out, G);
}

// Round 4
// 298.129 us; speedup vs baseline: 12.8299x; 1.6602x over previous
//
#include <hip/hip_runtime.h>
#include <hip/hip_bf16.h>
#include <math.h>

#define FH 128   // feature width of x and all hidden layers

typedef __attribute__((ext_vector_type(8))) short short8v;   // 8 bf16 (4 VGPRs)
typedef __attribute__((ext_vector_type(4))) float float4v;
typedef unsigned short ushort_t;
typedef unsigned int   uint32;

__device__ __forceinline__ ushort_t f2bf(float f) {          // RNE float->bf16
    uint32 u = __builtin_bit_cast(uint32, f);
    u += 0x7fffu + ((u >> 16) & 1u);
    return (ushort_t)(u >> 16);
}
__device__ __forceinline__ float bf_lo(uint32 w) { return __builtin_bit_cast(float, w << 16); }
__device__ __forceinline__ float bf_hi(uint32 w) { return __builtin_bit_cast(float, w & 0xffff0000u); }

// ---------------------------------------------------------------------------
// fp32 -> bf16 bulk convert (8 elems/thread)
__global__ __launch_bounds__(256) void cvt_bf16_kernel(const float* __restrict__ x,
                                                       ushort_t* __restrict__ xb, size_t n) {
    size_t base = ((size_t)blockIdx.x * 256 + threadIdx.x) * 8;
    if (base >= n) return;
    const float4 a = *(const float4*)(x + base);
    const float4 b = *(const float4*)(x + base + 4);
    ushort_t o[8] = {f2bf(a.x), f2bf(a.y), f2bf(a.z), f2bf(a.w),
                     f2bf(b.x), f2bf(b.y), f2bf(b.z), f2bf(b.w)};
    *(uint4*)(xb + base) = *(const uint4*)o;
}

// ---------------------------------------------------------------------------
// CSR build
__global__ __launch_bounds__(256) void deg_kernel(const int* __restrict__ dst,
                                                  int* __restrict__ deg, int E) {
    int e = blockIdx.x * 256 + threadIdx.x;
    if (e < E) atomicAdd(&deg[dst[e]], 1);
}

__global__ __launch_bounds__(256) void scan1_kernel(const int* __restrict__ deg,
                                                    int* __restrict__ rowptr,
                                                    int* __restrict__ blockSums, int N) {
    __shared__ int lds[256];
    const int base = blockIdx.x * 1024;
    const int t = threadIdx.x;
    int v[4]; int sum = 0;
    #pragma unroll
    for (int j = 0; j < 4; ++j) {
        int idx = base + t * 4 + j;
        v[j] = (idx < N) ? deg[idx] : 0;
        sum += v[j];
    }
    lds[t] = sum; __syncthreads();
    for (int off = 1; off < 256; off <<= 1) {
        int val = lds[t];
        int add = (t >= off) ? lds[t - off] : 0;
        __syncthreads();
        lds[t] = val + add;
        __syncthreads();
    }
    int run = (t > 0) ? lds[t - 1] : 0;
    #pragma unroll
    for (int j = 0; j < 4; ++j) {
        int idx = base + t * 4 + j;
        if (idx < N) rowptr[idx] = run;
        run += v[j];
    }
    if (t == 255) blockSums[blockIdx.x] = lds[255];
}

__global__ void scan2_kernel(int* __restrict__ blockSums, int* __restrict__ rowptr,
                             int nb, int N) {
    if (threadIdx.x == 0 && blockIdx.x == 0) {
        int carry = 0;
        for (int i = 0; i < nb; ++i) {
            int s = blockSums[i];
            blockSums[i] = carry;
            carry += s;
        }
        rowptr[N] = carry;   // == E
    }
}

__global__ __launch_bounds__(256) void scan3_kernel(int* __restrict__ rowptr,
                                                    const int* __restrict__ blockSums, int N) {
    const int base = blockIdx.x * 1024;
    const int add = blockSums[blockIdx.x];
    #pragma unroll
    for (int j = 0; j < 4; ++j) {
        int idx = base + threadIdx.x * 4 + j;
        if (idx < N) rowptr[idx] += add;
    }
}

__global__ __launch_bounds__(256) void copy_pos_kernel(const int* __restrict__ rowptr,
                                                       int* __restrict__ pos, int N) {
    int i = blockIdx.x * 256 + threadIdx.x;
    if (i < N) pos[i] = rowptr[i];
}

__global__ __launch_bounds__(256) void fill_csr_kernel(const int* __restrict__ src,
                                                       const int* __restrict__ dst,
                                                       int* __restrict__ pos,
                                                       int* __restrict__ csr, int E) {
    int e = blockIdx.x * 256 + threadIdx.x;
    if (e >= E) return;
    int idx = atomicAdd(&pos[dst[e]], 1);
    csr[idx] = src[e];
}

// ---------------------------------------------------------------------------
// pull aggregation (bf16 in/out, fp32 accumulate): one wave per dst node,
// 2 edges processed per iteration (32 lanes x uint2 per edge).
__global__ __launch_bounds__(256) void pull_mean_kernel(const ushort_t* __restrict__ x,
                                                        const int* __restrict__ rowptr,
                                                        const int* __restrict__ csr,
                                                        ushort_t* __restrict__ aggr, int N) {
    const int v = (blockIdx.x * 256 + threadIdx.x) >> 6;
    if (v >= N) return;
    const int lane = threadIdx.x & 63;
    const int half = lane >> 5;       // which edge of the pair
    const int c    = lane & 31;       // uint2 column (8 bytes = 4 bf16)
    const int beg = rowptr[v], end = rowptr[v + 1];
    const uint32* xp = (const uint32*)x + c * 2;
    float a0 = 0.f, a1 = 0.f, a2 = 0.f, a3 = 0.f;
    for (int i = beg + half; i < end; i += 2) {
        const int s = csr[i];
        const uint2 w = *(const uint2*)(xp + (size_t)s * 64);
        a0 += bf_lo(w.x); a1 += bf_hi(w.x);
        a2 += bf_lo(w.y); a3 += bf_hi(w.y);
    }
    // combine the two half-wave partials (feature c lives in lanes c and c+32)
    a0 += __shfl_xor(a0, 32);
    a1 += __shfl_xor(a1, 32);
    a2 += __shfl_xor(a2, 32);
    a3 += __shfl_xor(a3, 32);
    if (half == 0) {
        const float inv = 1.0f / (float)max(end - beg, 1);
        uint2 o;
        o.x = (uint32)f2bf(a0 * inv) | ((uint32)f2bf(a1 * inv) << 16);
        o.y = (uint32)f2bf(a2 * inv) | ((uint32)f2bf(a3 * inv) << 16);
        *(uint2*)((uint32*)aggr + (size_t)v * 64 + c * 2) = o;
    }
}

// ---------------------------------------------------------------------------
// pack W = [Wl;Wr] (256x128 fp32) into MFMA-fragment-ordered bf16:
// Bp[((nt*8+kt)*64 + lane)*8 + j] = W[k][n],
//   nt=n>>4, kt=k>>5, lane=(n&15)+16*((k>>3)&3), j=k&7
__global__ __launch_bounds__(256) void pack_w_kernel(const float* __restrict__ Wl,
                                                     const float* __restrict__ Wr,
                                                     ushort_t* __restrict__ Bp) {
    int t = blockIdx.x * 256 + threadIdx.x;
    if (t >= 256 * FH) return;
    int k = t >> 7, n = t & 127;
    float v = (k < FH) ? Wl[k * FH + n] : Wr[(k - FH) * FH + n];
    int nt = n >> 4, kt = k >> 5;
    int lane = (n & 15) + (((k >> 3) & 3) << 4);
    int j = k & 7;
    Bp[(((nt * 8 + kt) * 64) + lane) * 8 + j] = f2bf(v);
}

// ---------------------------------------------------------------------------
// fused SAGE layer via MFMA: out = relu([aggr|xin](Mx256) @ W(256x128) + bl)
// 4 waves/block, 16 rows/wave; full weight tile staged in LDS (64KB).
// In-place safe: rows are loaded to registers before any store; rows are
// wave-exclusive and out[row] depends only on row's own inputs.
__global__ __launch_bounds__(256) void sage_mfma_kernel(const ushort_t* __restrict__ xin,
                                                        const ushort_t* __restrict__ aggr,
                                                        const ushort_t* __restrict__ Bp,
                                                        const float* __restrict__ bl,
                                                        ushort_t* __restrict__ out, int M) {
    __shared__ ushort_t sB[8 * 8 * 64 * 8];   // 64 KB
    const int tid = threadIdx.x;
    {   // cooperative 64KB load: 4096 x 16B
        const uint4* s = (const uint4*)Bp;
        uint4* d = (uint4*)sB;
        #pragma unroll
        for (int i = 0; i < 16; ++i)
            d[tid + 256 * i] = s[tid + 256 * i];
    }
    __syncthreads();

    const int wave = tid >> 6;
    const int lane = tid & 63;
    const int grp  = lane >> 4;
    const int rowBase = (blockIdx.x * 4 + wave) * 16;
    if (rowBase >= M) return;
    const int arow = min(rowBase + (lane & 15), M - 1);

    short8v afrag[8];
    #pragma unroll
    for (int kt = 0; kt < 4; ++kt)
        afrag[kt] = *(const short8v*)(aggr + (size_t)arow * FH + kt * 32 + grp * 8);
    #pragma unroll
    for (int kt = 0; kt < 4; ++kt)
        afrag[4 + kt] = *(const short8v*)(xin + (size_t)arow * FH + kt * 32 + grp * 8);

    #pragma unroll
    for (int nt = 0; nt < 8; ++nt) {
        float4v acc = {0.f, 0.f, 0.f, 0.f};
        #pragma unroll
        for (int kt = 0; kt < 8; ++kt) {
            const short8v b = *(const short8v*)(sB + (((nt * 8 + kt) * 64) + lane) * 8);
            acc = __builtin_amdgcn_mfma_f32_16x16x32_bf16(afrag[kt], b, acc, 0, 0, 0);
        }
        const int col = nt * 16 + (lane & 15);
        const float bias = bl[col];
        #pragma unroll
        for (int r = 0; r < 4; ++r) {
            const int row = rowBase + grp * 4 + r;
            if (row < M)
                out[(size_t)row * FH + col] = f2bf(fmaxf(acc[r] + bias, 0.f));
        }
    }
}

// ---------------------------------------------------------------------------
// batch is SORTED: gstart[g] = lower_bound(batch, g); gstart[G] = N
__global__ __launch_bounds__(256) void group_bounds_kernel(const int* __restrict__ batch,
                                                           int* __restrict__ gstart,
                                                           int N, int G) {
    int g = blockIdx.x * 256 + threadIdx.x;
    if (g > G) return;
    int lo = 0, hi = N;
    while (lo < hi) {
        int mid = (lo + hi) >> 1;
        if (batch[mid] < g) lo = mid + 1; else hi = mid;
    }
    gstart[g] = lo;
}

// one block per group: stream contiguous rows, no atomics; writes the MEAN
__global__ __launch_bounds__(256) void pool_mean_kernel(const ushort_t* __restrict__ h,
                                                        const int* __restrict__ gstart,
                                                        float* __restrict__ gmean, int G) {
    __shared__ float sred[4][FH];
    const int g = blockIdx.x;
    const int t = threadIdx.x;
    const int wave = t >> 6, lane = t & 63;
    const int beg = gstart[g], end = gstart[g + 1];
    const uint32* hp = (const uint32*)h + lane;
    float a0 = 0.f, a1 = 0.f;
    for (int i = beg + wave; i < end; i += 4) {
        const uint32 w = hp[(size_t)i * 64];
        a0 += bf_lo(w); a1 += bf_hi(w);
    }
    sred[wave][lane * 2]     = a0;
    sred[wave][lane * 2 + 1] = a1;
    __syncthreads();
    if (t < FH) {
        const float s = sred[0][t] + sred[1][t] + sred[2][t] + sred[3][t];
        gmean[g * FH + t] = s / (float)max(end - beg, 1);
    }
}

// ---------------------------------------------------------------------------
// g2 = relu( gmean @ W4 + b4 )
__global__ __launch_bounds__(256) void mlp1_kernel(const float* __restrict__ gmean,
                                                   const float* __restrict__ W4,
                                                   const float* __restrict__ b4,
                                                   float* __restrict__ g2, int G) {
    int t = blockIdx.x * 256 + threadIdx.x;
    if (t >= G * 64) return;
    int g = t >> 6, j = t & 63;
    float acc = b4[j];
    #pragma unroll 4
    for (int k = 0; k < FH; ++k)
        acc += gmean[g * FH + k] * W4[k * 64 + j];
    g2[g * 64 + j] = fmaxf(acc, 0.f);
}

__global__ __launch_bounds__(256) void mlp2_kernel(const float* __restrict__ g2,
                                                   const float* __restrict__ W5,
                                                   const float* __restrict__ b5,
                                                   float* __restrict__ out, int G) {
    int g = blockIdx.x * 256 + threadIdx.x;
    if (g >= G) return;
    float l[10];
    #pragma unroll
    for (int j = 0; j < 10; ++j) l[j] = b5[j];
    for (int k = 0; k < 64; ++k) {
        float v = g2[g * 64 + k];
        #pragma unroll
        for (int j = 0; j < 10; ++j) l[j] += v * W5[k * 10 + j];
    }
    float m = l[0];
    #pragma unroll
    for (int j = 1; j < 10; ++j) m = fmaxf(m, l[j]);
    float s = 0.f;
    #pragma unroll
    for (int j = 0; j < 10; ++j) s += expf(l[j] - m);
    float lse = m + logf(s);
    #pragma unroll
    for (int j = 0; j < 10; ++j) out[g * 10 + j] = l[j] - lse;
}

// ---------------------------------------------------------------------------
extern "C" void kernel_launch(void* const* d_in, const int* in_sizes, int n_in,
                              void* d_out, int out_size, void* d_ws, size_t ws_size,
                              hipStream_t stream) {
    const float* x     = (const float*)d_in[0];
    const int*   ei    = (const int*)d_in[1];
    const int*   batch = (const int*)d_in[2];
    const float* Wl1 = (const float*)d_in[3];
    const float* bl1 = (const float*)d_in[4];
    const float* Wr1 = (const float*)d_in[5];
    const float* Wl2 = (const float*)d_in[6];
    const float* bl2 = (const float*)d_in[7];
    const float* Wr2 = (const float*)d_in[8];
    const float* Wl3 = (const float*)d_in[9];
    const float* bl3 = (const float*)d_in[10];
    const float* Wr3 = (const float*)d_in[11];
    const float* W4  = (const float*)d_in[12];
    const float* b4  = (const float*)d_in[13];
    const float* W5  = (const float*)d_in[14];
    const float* b5  = (const float*)d_in[15];
    float* out = (float*)d_out;

    const int N = in_sizes[0] / FH;   // 50000
    const int E = in_sizes[1] / 2;    // 600000
    const int G = out_size / 10;      // 500
    const int* src = ei;
    const int* dst = ei + E;

    // ---- workspace layout (256B-aligned chunks)
    char* p = (char*)d_ws;
    auto take = [&](size_t bytes) { char* q = p; p += (bytes + 255) & ~(size_t)255; return q; };
    ushort_t* xb    = (ushort_t*)take((size_t)N * FH * 2);
    ushort_t* h     = (ushort_t*)take((size_t)N * FH * 2);
    ushort_t* aggrb = (ushort_t*)take((size_t)N * FH * 2);
    int* deg        = (int*)take((size_t)N * 4);
    int* rowptr     = (int*)take((size_t)(N + 1) * 4);
    int* pos        = (int*)take((size_t)N * 4);
    int* csr        = (int*)take((size_t)E * 4);
    int* blockSums  = (int*)take(256 * 4);
    ushort_t* Bp1   = (ushort_t*)take(256 * FH * 2);
    ushort_t* Bp2   = (ushort_t*)take(256 * FH * 2);
    ushort_t* Bp3   = (ushort_t*)take(256 * FH * 2);
    int* gstart     = (int*)take((size_t)(G + 1) * 4);
    float* gmean    = (float*)take((size_t)G * FH * 4);
    float* g2       = (float*)take((size_t)G * 64 * 4);

    const int nb = (N + 1023) / 1024;

    hipMemsetAsync(deg, 0, (size_t)N * 4, stream);

    // ---- one-time converts / packs
    cvt_bf16_kernel<<<(N * FH / 8 + 255) / 256, 256, 0, stream>>>(x, xb, (size_t)N * FH);
    pack_w_kernel<<<(256 * FH + 255) / 256, 256, 0, stream>>>(Wl1, Wr1, Bp1);
    pack_w_kernel<<<(256 * FH + 255) / 256, 256, 0, stream>>>(Wl2, Wr2, Bp2);
    pack_w_kernel<<<(256 * FH + 255) / 256, 256, 0, stream>>>(Wl3, Wr3, Bp3);

    // ---- CSR build
    deg_kernel<<<(E + 255) / 256, 256, 0, stream>>>(dst, deg, E);
    scan1_kernel<<<nb, 256, 0, stream>>>(deg, rowptr, blockSums, N);
    scan2_kernel<<<1, 64, 0, stream>>>(blockSums, rowptr, nb, N);
    scan3_kernel<<<nb, 256, 0, stream>>>(rowptr, blockSums, N);
    copy_pos_kernel<<<(N + 255) / 256, 256, 0, stream>>>(rowptr, pos, N);
    fill_csr_kernel<<<(E + 255) / 256, 256, 0, stream>>>(src, dst, pos, csr, E);

    // ---- group bounds from sorted batch
    group_bounds_kernel<<<(G + 256) / 256, 256, 0, stream>>>(batch, gstart, N, G);

    const int pullGrid = (N * 64 + 255) / 256;
    const int gemmGrid = (N + 63) / 64;

    // ---- 3 SAGE layers (bf16 features, fp32 accum)
    pull_mean_kernel<<<pullGrid, 256, 0, stream>>>(xb, rowptr, csr, aggrb, N);
    sage_mfma_kernel<<<gemmGrid, 256, 0, stream>>>(xb, aggrb, Bp1, bl1, h, N);

    pull_mean_kernel<<<pullGrid, 256, 0, stream>>>(h, rowptr, csr, aggrb, N);
    sage_mfma_kernel<<<gemmGrid, 256, 0, stream>>>(h, aggrb, Bp2, bl2, h, N);

    pull_mean_kernel<<<pullGrid, 256, 0, stream>>>(h, rowptr, csr, aggrb, N);
    sage_mfma_kernel<<<gemmGrid, 256, 0, stream>>>(h, aggrb, Bp3, bl3, h, N);

    // ---- global mean pool (no atomics) + head
    pool_mean_kernel<<<G, 256, 0, stream>>>(h, gstart, gmean, G);
    mlp1_kernel<<<(G * 64 + 255) / 256, 256, 0, stream>>>(gmean, W4, b4, g2, G);
    mlp2_kernel<<<(G + 255) / 256, 256, 0, stream>>>(g2, W5, b5, out, G);
}